// Round 2
// baseline (2977.591 us; speedup 1.0000x reference)
//
#include <hip/hip_runtime.h>
#include <stdint.h>

#define NPTS 2048
#define NB 4
#define NROWS (NB * NPTS)
#define LNEG 0.2f

static __device__ __forceinline__ uint32_t sortable_f32(float f) {
  uint32_t u = __float_as_uint(f);
  return u ^ ((u >> 31) ? 0xFFFFFFFFu : 0x80000000u);
}

// ---------------- local_idx dtype detect (bool u8 vs i32 vs i64) ----------------
__global__ void detect_mode_k(const uint32_t* __restrict__ loc, int* __restrict__ mode) {
  __shared__ uint32_t mAll, mOdd;
  if (threadIdx.x == 0) { mAll = 0u; mOdd = 0u; }
  __syncthreads();
  uint32_t a = 0u, o = 0u;
  for (int i = threadIdx.x; i < 2048; i += 256) {  // 8192 bytes: safe for every mode
    uint32_t v = loc[i];
    a = a > v ? a : v;
    if (i & 1) o = o > v ? o : v;
  }
  atomicMax(&mAll, a);
  atomicMax(&mOdd, o);
  __syncthreads();
  if (threadIdx.x == 0) {
    int m;
    if (mAll > 1u) m = 0;        // packed 1-byte bool
    else if (mOdd == 0u) m = 2;  // int64 (odd u32 words all zero)
    else m = 1;                  // int32
    *mode = m;
  }
}

__device__ __forceinline__ bool read_allow(const void* loc, int mode, int i) {
  if (mode == 0) return ((const uint8_t*)loc)[i] != 0;
  if (mode == 1) return ((const int*)loc)[i] != 0;
  return ((const uint32_t*)loc)[(size_t)i * 2] != 0;  // little-endian low word
}

// ---------------- prep: x transpose, weight transforms, BN fold ----------------
struct PrepArgs {
  const float* x; float* x0;
  const float* w[9]; float* wt[9];
  int O[9], C[9];
  const float* bn[11]; float* bns[11]; float* bnb[11];
  int bc[11];
};

__global__ void prep_k(PrepArgs pa) {
  int idx = blockIdx.x * 256 + threadIdx.x;
  if (idx < NROWS * 3) {               // x (B,3,N) -> x0 (B*N, 3)
    int c = idx % 3, r = idx / 3;
    int b = r >> 11, n = r & (NPTS - 1);
    pa.x0[idx] = pa.x[((size_t)b * 3 + c) * NPTS + n];
    return;
  }
  idx -= NROWS * 3;
  #pragma unroll
  for (int l = 0; l < 9; ++l) {
    int O = pa.O[l], C = pa.C[l];
    int n2 = (l == 8) ? O : 2 * O;
    int sz = C * n2;
    if (idx < sz) {
      int o = idx % n2, c = idx / n2;
      float v;
      if (l == 8) v = pa.w[l][(size_t)o * C + c];                     // plain transpose of w9
      else if (o < O) v = pa.w[l][(size_t)o * 2 * C + c];             // wA
      else v = pa.w[l][(size_t)(o - O) * 2 * C + C + c]
             - pa.w[l][(size_t)(o - O) * 2 * C + c];                  // wB - wA
      pa.wt[l][(size_t)c * n2 + o] = v;
      return;
    }
    idx -= sz;
  }
  #pragma unroll
  for (int i = 0; i < 11; ++i) {
    int C = pa.bc[i];
    if (idx < C) {
      float g = pa.bn[i][idx], b = pa.bn[i][C + idx];
      float m = pa.bn[i][2 * C + idx], v = pa.bn[i][3 * C + idx];
      float s = g * rsqrtf(v + 1e-5f);
      pa.bns[i][idx] = s;
      pa.bnb[i][idx] = b - m * s;
      return;
    }
    idx -= C;
  }
}

// ---------------- kNN: exact jax top_k replication (value desc, index asc) -----
__global__ __launch_bounds__(256) void knn_k(const float* __restrict__ geod,
                                             const void* __restrict__ loc,
                                             const int* __restrict__ modep,
                                             int* __restrict__ idxL,
                                             int* __restrict__ idxG) {
  int row = blockIdx.x;
  int b = row >> 11;
  int tid = threadIdx.x;
  int wid = tid >> 6, lane = tid & 63;
  int mode = *modep;
  const float* g = geod + (size_t)row * NPTS;

  float v[8]; bool al[8];
  float lmin = INFINITY;
  #pragma unroll
  for (int e = 0; e < 8; ++e) {
    int j = tid + 256 * e;
    v[e] = g[j];
    al[e] = read_allow(loc, mode, b * NPTS + j);
    lmin = fminf(lmin, v[e]);
  }
  __shared__ float sred[4];
  #pragma unroll
  for (int off = 32; off; off >>= 1) lmin = fminf(lmin, __shfl_xor(lmin, off));
  if (lane == 0) sred[wid] = lmin;
  __syncthreads();
  lmin = fminf(fminf(sred[0], sred[1]), fminf(sred[2], sred[3]));

  uint32_t smin = sortable_f32(lmin);
  unsigned long long keyL[8], keyG[8];
  #pragma unroll
  for (int e = 0; e < 8; ++e) {
    int j = tid + 256 * e;
    uint32_t sv = sortable_f32(v[e]);
    uint32_t kl = al[e] ? sv : smin;   // local conv: allowed = local_idx
    uint32_t kg = al[e] ? smin : sv;   // global conv: allowed = ~local_idx
    keyL[e] = ((unsigned long long)kl << 11) | (unsigned)(NPTS - 1 - j);
    keyG[e] = ((unsigned long long)kg << 11) | (unsigned)(NPTS - 1 - j);
  }

  __shared__ unsigned long long skey[4];
  auto runsel = [&](unsigned long long* key, int K, int* outp) {
    // cached per-thread running max: only the extraction owner rescans its 8 keys
    unsigned long long tmax = key[0];
    #pragma unroll
    for (int e = 1; e < 8; ++e) tmax = tmax > key[e] ? tmax : key[e];
    for (int it = 0; it < K; ++it) {
      unsigned long long m = tmax;
      #pragma unroll
      for (int off = 32; off; off >>= 1) {
        unsigned lo = __shfl_xor((unsigned)m, off);
        unsigned hi = __shfl_xor((unsigned)(m >> 32), off);
        unsigned long long om = ((unsigned long long)hi << 32) | lo;
        m = m > om ? m : om;
      }
      if (lane == 0) skey[wid] = m;
      __syncthreads();
      unsigned long long M = skey[0];
      #pragma unroll
      for (int w = 1; w < 4; ++w) M = M > skey[w] ? M : skey[w];
      int j = (NPTS - 1) - (int)(M & (unsigned long long)(NPTS - 1));
      if (tid == 0) outp[it] = j;
      if ((j & 255) == tid) {          // this thread owned the extracted key
        key[j >> 8] = 0ull;
        tmax = key[0];
        #pragma unroll
        for (int e = 1; e < 8; ++e) tmax = tmax > key[e] ? tmax : key[e];
      }
      __syncthreads();                 // skey consumed by all before next write
    }
  };
  runsel(keyL, 16, idxL + (size_t)row * 16);
  runsel(keyG, 32, idxG + (size_t)row * 32);
}

// ---------------- fp32 tiled GEMM 64x64: C = A(MxK) * Bt(KxN2) ----------------
#define BM 64
#define BNC 64
#define BKC 16

__global__ __launch_bounds__(256) void gemm_k(const float* __restrict__ A, int lda,
                                              const float* __restrict__ Bt, int K, int N2,
                                              float* __restrict__ C, int ldc,
                                              const float* __restrict__ sc,
                                              const float* __restrict__ bi, int act) {
  __shared__ float As[BKC][BM + 4];   // row stride 272B = 16B-aligned
  __shared__ float Bs[BKC][BNC + 4];
  int tid = threadIdx.x;
  int tx = tid & 15, ty = tid >> 4;
  int m0 = blockIdx.x * BM, n0 = blockIdx.y * BNC;
  float acc[4][4] = {};
  for (int k0 = 0; k0 < K; k0 += BKC) {
    #pragma unroll
    for (int i = tid; i < BM * BKC; i += 256) {
      int kk = i & 15, mm = i >> 4;
      int kg = k0 + kk;
      As[kk][mm] = (kg < K) ? A[(size_t)(m0 + mm) * lda + kg] : 0.f;
    }
    #pragma unroll
    for (int i = tid; i < BKC * BNC; i += 256) {
      int nn = i & 63, kk = i >> 6;
      int kg = k0 + kk;
      Bs[kk][nn] = (kg < K) ? Bt[(size_t)kg * N2 + n0 + nn] : 0.f;
    }
    __syncthreads();
    #pragma unroll
    for (int k = 0; k < BKC; ++k) {
      float4 a4 = *(const float4*)&As[k][tx * 4];
      float4 b4 = *(const float4*)&Bs[k][ty * 4];
      float a[4] = {a4.x, a4.y, a4.z, a4.w};
      float bb[4] = {b4.x, b4.y, b4.z, b4.w};
      #pragma unroll
      for (int i2 = 0; i2 < 4; ++i2)
        #pragma unroll
        for (int j2 = 0; j2 < 4; ++j2)
          acc[i2][j2] = fmaf(a[i2], bb[j2], acc[i2][j2]);
    }
    __syncthreads();
  }
  #pragma unroll
  for (int i2 = 0; i2 < 4; ++i2) {
    int m = m0 + tx * 4 + i2;
    float4 o4;
    float* ov = (float*)&o4;
    #pragma unroll
    for (int j2 = 0; j2 < 4; ++j2) {
      int n = n0 + ty * 4 + j2;
      float vv = acc[i2][j2];
      if (act) {
        vv = fmaf(vv, sc[n], bi[n]);
        vv = vv >= 0.f ? vv : LNEG * vv;
      }
      ov[j2] = vv;
    }
    *(float4*)&C[(size_t)m * ldc + n0 + ty * 4] = o4;
  }
}

// ---------------- fp32 tiled GEMM 128x128 (8x8/thread) for the big layers ------
#define BM2 128
#define BN2 128
#define BK2 16

__global__ __launch_bounds__(256) void gemm128_k(const float* __restrict__ A, int lda,
                                                 const float* __restrict__ Bt, int K, int N2,
                                                 float* __restrict__ C, int ldc,
                                                 const float* __restrict__ sc,
                                                 const float* __restrict__ bi, int act) {
  __shared__ float As[BK2][BM2 + 4];  // row stride 528B = 16B-aligned
  __shared__ float Bs[BK2][BN2 + 4];
  int tid = threadIdx.x;
  int tx = tid & 15, ty = tid >> 4;
  int m0 = blockIdx.x * BM2, n0 = blockIdx.y * BN2;
  float acc[8][8] = {};
  for (int k0 = 0; k0 < K; k0 += BK2) {
    #pragma unroll
    for (int i = tid; i < BM2 * BK2; i += 256) {
      int kk = i & 15, mm = i >> 4;
      int kg = k0 + kk;
      As[kk][mm] = (kg < K) ? A[(size_t)(m0 + mm) * lda + kg] : 0.f;
    }
    #pragma unroll
    for (int i = tid; i < BK2 * BN2; i += 256) {
      int nn = i & 127, kk = i >> 7;
      int kg = k0 + kk;
      Bs[kk][nn] = (kg < K) ? Bt[(size_t)kg * N2 + n0 + nn] : 0.f;
    }
    __syncthreads();
    #pragma unroll
    for (int k = 0; k < BK2; ++k) {
      float a[8], bb[8];
      *(float4*)&a[0]  = *(const float4*)&As[k][tx * 8];
      *(float4*)&a[4]  = *(const float4*)&As[k][tx * 8 + 4];
      *(float4*)&bb[0] = *(const float4*)&Bs[k][ty * 8];
      *(float4*)&bb[4] = *(const float4*)&Bs[k][ty * 8 + 4];
      #pragma unroll
      for (int i2 = 0; i2 < 8; ++i2)
        #pragma unroll
        for (int j2 = 0; j2 < 8; ++j2)
          acc[i2][j2] = fmaf(a[i2], bb[j2], acc[i2][j2]);
    }
    __syncthreads();
  }
  #pragma unroll
  for (int i2 = 0; i2 < 8; ++i2) {
    int m = m0 + tx * 8 + i2;
    float4 o4a, o4b;
    float* ov = (float*)&o4a;
    float* ow = (float*)&o4b;
    #pragma unroll
    for (int j2 = 0; j2 < 8; ++j2) {
      int n = n0 + ty * 8 + j2;
      float vv = acc[i2][j2];
      if (act) {
        vv = fmaf(vv, sc[n], bi[n]);
        vv = vv >= 0.f ? vv : LNEG * vv;
      }
      if (j2 < 4) ov[j2] = vv; else ow[j2 - 4] = vv;
    }
    *(float4*)&C[(size_t)m * ldc + n0 + ty * 8] = o4a;
    *(float4*)&C[(size_t)m * ldc + n0 + ty * 8 + 4] = o4b;
  }
}

// ---------------- gather-max + BN + leaky: one wave per point ------------------
template<int K, int O>
__global__ __launch_bounds__(256) void gather_k(const float* __restrict__ z,
                                                const int* __restrict__ idx,
                                                const float* __restrict__ scale,
                                                const float* __restrict__ bias,
                                                float* __restrict__ outp) {
  constexpr int LDZ = 2 * O;
  int wid = threadIdx.x >> 6, lane = threadIdx.x & 63;
  int point = (blockIdx.x << 2) + wid;
  int b = point >> 11;
  const int* ip = idx + (size_t)point * K;
  int jj[K];
  #pragma unroll
  for (int k = 0; k < K; ++k) jj[k] = ip[k];
  #pragma unroll
  for (int c0 = 0; c0 < O; c0 += 64) {
    int c = c0 + lane;
    float mx = -INFINITY, mn = INFINITY;
    #pragma unroll
    for (int k = 0; k < K; ++k) {
      float v = z[(size_t)((b << 11) + jj[k]) * LDZ + c];
      mx = fmaxf(mx, v);
      mn = fminf(mn, v);
    }
    float zc = z[(size_t)point * LDZ + O + c];
    float s = scale[c], bb = bias[c];
    float val = (s >= 0.f ? mx : mn) + zc;     // max commutes through monotone BN+leaky
    float t = fmaf(val, s, bb);
    outp[(size_t)point * 512 + c] = t >= 0.f ? t : LNEG * t;
  }
}

// ---------------- xm = local_idx ? xcatL : xcatG ------------------------------
__global__ __launch_bounds__(256) void select_k(const float* __restrict__ xl,
                                                const float* __restrict__ xg,
                                                const void* __restrict__ loc,
                                                const int* __restrict__ modep,
                                                float* __restrict__ xm) {
  int i = blockIdx.x * 256 + threadIdx.x;   // over NROWS*128 float4
  int row = i >> 7;
  int mode = *modep;
  bool l = read_allow(loc, mode, row);
  const float4* s = (const float4*)(l ? xl : xg);
  ((float4*)xm)[i] = s[i];
}

// ---------------- per-(b,channel) max & mean over n ---------------------------
__global__ __launch_bounds__(256) void reduce_np_k(const float* __restrict__ y,
                                                   float* __restrict__ p) {
  int b = blockIdx.x >> 4, cb = blockIdx.x & 15;
  int wid = threadIdx.x >> 6, lane = threadIdx.x & 63;
  int c = cb * 64 + lane;
  float mx = -INFINITY, sm = 0.f;
  for (int n = wid; n < NPTS; n += 4) {
    float v = y[((size_t)(b * NPTS + n)) * 1024 + c];
    mx = fmaxf(mx, v);
    sm += v;
  }
  __shared__ float smx[4][64], ssm[4][64];
  smx[wid][lane] = mx;
  ssm[wid][lane] = sm;
  __syncthreads();
  if (wid == 0) {
    #pragma unroll
    for (int w = 1; w < 4; ++w) { mx = fmaxf(mx, smx[w][lane]); sm += ssm[w][lane]; }
    p[b * 2048 + c] = mx;
    p[b * 2048 + 1024 + c] = sm * (1.f / 2048.f);
  }
}

// ---------------- final MLP (tiny): one block per batch -----------------------
__global__ __launch_bounds__(256) void mlp_k(const float* __restrict__ p,
                                             const float* __restrict__ l1w,
                                             const float* __restrict__ l2w,
                                             const float* __restrict__ l2b,
                                             const float* __restrict__ l3w,
                                             const float* __restrict__ l3b,
                                             const float* __restrict__ s10,
                                             const float* __restrict__ b10,
                                             const float* __restrict__ s11,
                                             const float* __restrict__ b11,
                                             float* __restrict__ outp) {
  int b = blockIdx.x;
  int wid = threadIdx.x >> 6, lane = threadIdx.x & 63;
  __shared__ float sp[2048];
  __shared__ float h1[512];
  __shared__ float h2[256];
  for (int i = threadIdx.x; i < 2048; i += 256) sp[i] = p[b * 2048 + i];
  __syncthreads();
  for (int o = wid; o < 512; o += 4) {
    const float* w = l1w + (size_t)o * 2048;
    float acc = 0.f;
    for (int c = lane; c < 2048; c += 64) acc += w[c] * sp[c];
    #pragma unroll
    for (int off = 32; off; off >>= 1) acc += __shfl_xor(acc, off);
    if (lane == 0) {
      float t = fmaf(acc, s10[o], b10[o]);
      h1[o] = t >= 0.f ? t : LNEG * t;
    }
  }
  __syncthreads();
  for (int o = wid; o < 256; o += 4) {
    const float* w = l2w + (size_t)o * 512;
    float acc = 0.f;
    for (int c = lane; c < 512; c += 64) acc += w[c] * h1[c];
    #pragma unroll
    for (int off = 32; off; off >>= 1) acc += __shfl_xor(acc, off);
    if (lane == 0) {
      float t = fmaf(acc + l2b[o], s11[o], b11[o]);
      h2[o] = t >= 0.f ? t : LNEG * t;
    }
  }
  __syncthreads();
  for (int o = wid; o < 40; o += 4) {
    const float* w = l3w + (size_t)o * 256;
    float acc = 0.f;
    for (int c = lane; c < 256; c += 64) acc += w[c] * h2[c];
    #pragma unroll
    for (int off = 32; off; off >>= 1) acc += __shfl_xor(acc, off);
    if (lane == 0) outp[b * 40 + o] = acc + l3b[o];
  }
}

// ---------------- host orchestration ------------------------------------------
extern "C" void kernel_launch(void* const* d_in, const int* in_sizes, int n_in,
                              void* d_out, int out_size, void* d_ws, size_t ws_size,
                              hipStream_t stream) {
  const float* x = (const float*)d_in[0];
  const void* loc = d_in[1];
  const float* geod = (const float*)d_in[2];
  const float* w[9];
  for (int i = 0; i < 9; ++i) w[i] = (const float*)d_in[3 + i];
  const float* bn[11];
  for (int i = 0; i < 11; ++i) bn[i] = (const float*)d_in[12 + i];
  const float* l1w = (const float*)d_in[23];
  const float* l2w = (const float*)d_in[24];
  const float* l2b = (const float*)d_in[25];
  const float* l3w = (const float*)d_in[26];
  const float* l3b = (const float*)d_in[27];
  float* outp = (float*)d_out;

  char* base = (char*)d_ws;
  size_t off = 0;
  auto alloc = [&](size_t bytes) -> void* {
    void* p = base + off;
    off += (bytes + 255) & ~(size_t)255;
    return p;
  };
  int* mode = (int*)alloc(4);
  float* x0 = (float*)alloc((size_t)NROWS * 3 * 4);
  int* idxL = (int*)alloc((size_t)NROWS * 16 * 4);
  int* idxG = (int*)alloc((size_t)NROWS * 32 * 4);
  static const int Oc[9] = {64, 64, 128, 256, 64, 64, 128, 256, 1024};
  static const int Cc[9] = {3, 64, 64, 128, 3, 64, 64, 128, 512};
  float* wt[9];
  for (int l = 0; l < 9; ++l) {
    int n2 = (l == 8) ? Oc[l] : 2 * Oc[l];
    wt[l] = (float*)alloc((size_t)Cc[l] * n2 * 4);
  }
  static const int bc[11] = {64, 64, 128, 256, 64, 64, 128, 256, 1024, 512, 256};
  float *bns[11], *bnb[11];
  for (int i = 0; i < 11; ++i) {
    bns[i] = (float*)alloc((size_t)bc[i] * 4);
    bnb[i] = (float*)alloc((size_t)bc[i] * 4);
  }
  float* z = (float*)alloc((size_t)NROWS * 1024 * 4);      // reused: conv z / layer-9 y
  float* xcatL = (float*)alloc((size_t)NROWS * 512 * 4);
  float* xcatG = (float*)alloc((size_t)NROWS * 512 * 4);
  float* xm = (float*)alloc((size_t)NROWS * 512 * 4);
  float* pbuf = (float*)alloc((size_t)NB * 2048 * 4);

  detect_mode_k<<<1, 256, 0, stream>>>((const uint32_t*)loc, mode);

  PrepArgs pa;
  pa.x = x; pa.x0 = x0;
  for (int l = 0; l < 9; ++l) { pa.w[l] = w[l]; pa.wt[l] = wt[l]; pa.O[l] = Oc[l]; pa.C[l] = Cc[l]; }
  for (int i = 0; i < 11; ++i) { pa.bn[i] = bn[i]; pa.bns[i] = bns[i]; pa.bnb[i] = bnb[i]; pa.bc[i] = bc[i]; }
  int total = NROWS * 3;
  for (int l = 0; l < 9; ++l) total += Cc[l] * ((l == 8) ? Oc[l] : 2 * Oc[l]);
  for (int i = 0; i < 11; ++i) total += bc[i];
  prep_k<<<(total + 255) / 256, 256, 0, stream>>>(pa);

  knn_k<<<NROWS, 256, 0, stream>>>(geod, loc, mode, idxL, idxG);

  auto gemm = [&](const float* A, int lda, const float* Bt, int K, int N2, float* C, int ldc,
                  const float* sc, const float* bi, int act) {
    if (N2 >= 512) {
      dim3 grid(NROWS / BM2, N2 / BN2);
      gemm128_k<<<grid, 256, 0, stream>>>(A, lda, Bt, K, N2, C, ldc, sc, bi, act);
    } else {
      dim3 grid(NROWS / BM, N2 / BNC);
      gemm_k<<<grid, 256, 0, stream>>>(A, lda, Bt, K, N2, C, ldc, sc, bi, act);
    }
  };
  auto gather = [&](int K, int O, const int* idx, const float* sc, const float* bi, float* op) {
    dim3 grid(NROWS / 4);
    if (K == 16) {
      if (O == 64)       gather_k<16, 64><<<grid, 256, 0, stream>>>(z, idx, sc, bi, op);
      else if (O == 128) gather_k<16, 128><<<grid, 256, 0, stream>>>(z, idx, sc, bi, op);
      else               gather_k<16, 256><<<grid, 256, 0, stream>>>(z, idx, sc, bi, op);
    } else {
      if (O == 64)       gather_k<32, 64><<<grid, 256, 0, stream>>>(z, idx, sc, bi, op);
      else if (O == 128) gather_k<32, 128><<<grid, 256, 0, stream>>>(z, idx, sc, bi, op);
      else               gather_k<32, 256><<<grid, 256, 0, stream>>>(z, idx, sc, bi, op);
    }
  };

  static const int coff[4] = {0, 64, 128, 256};
  for (int l = 0; l < 4; ++l) {   // local chain (K=16, w1-4, bn1-4)
    const float* A = (l == 0) ? x0 : (xcatL + coff[l - 1]);
    int lda = (l == 0) ? 3 : 512;
    gemm(A, lda, wt[l], Cc[l], 2 * Oc[l], z, 2 * Oc[l], nullptr, nullptr, 0);
    gather(16, Oc[l], idxL, bns[l], bnb[l], xcatL + coff[l]);
  }
  for (int l = 0; l < 4; ++l) {   // global chain (K=32, w5-8, bn5-8)
    const float* A = (l == 0) ? x0 : (xcatG + coff[l - 1]);
    int lda = (l == 0) ? 3 : 512;
    gemm(A, lda, wt[4 + l], Cc[4 + l], 2 * Oc[4 + l], z, 2 * Oc[4 + l], nullptr, nullptr, 0);
    gather(32, Oc[4 + l], idxG, bns[4 + l], bnb[4 + l], xcatG + coff[l]);
  }

  select_k<<<(NROWS * 512 / 4) / 256, 256, 0, stream>>>(xcatL, xcatG, loc, mode, xm);
  gemm(xm, 512, wt[8], 512, 1024, z, 1024, bns[8], bnb[8], 1);   // layer 9 + BN9 + leaky fused
  reduce_np_k<<<NB * 16, 256, 0, stream>>>(z, pbuf);
  mlp_k<<<NB, 256, 0, stream>>>(pbuf, l1w, l2w, l2b, l3w, l3b,
                                bns[9], bnb[9], bns[10], bnb[10], outp);
}

// Round 4
// 1108.504 us; speedup vs baseline: 2.6861x; 2.6861x over previous
//
#include <hip/hip_runtime.h>
#include <stdint.h>

#define NPTS 2048
#define NB 4
#define NROWS (NB * NPTS)
#define LNEG 0.2f

static __device__ __forceinline__ uint32_t sortable_f32(float f) {
  uint32_t u = __float_as_uint(f);
  return u ^ ((u >> 31) ? 0xFFFFFFFFu : 0x80000000u);
}

// ---------------- local_idx dtype detect (bool u8 vs i32 vs i64) ----------------
__global__ void detect_mode_k(const uint32_t* __restrict__ loc, int* __restrict__ mode) {
  __shared__ uint32_t mAll, mOdd;
  if (threadIdx.x == 0) { mAll = 0u; mOdd = 0u; }
  __syncthreads();
  uint32_t a = 0u, o = 0u;
  for (int i = threadIdx.x; i < 2048; i += 256) {  // 8192 bytes: safe for every mode
    uint32_t v = loc[i];
    a = a > v ? a : v;
    if (i & 1) o = o > v ? o : v;
  }
  atomicMax(&mAll, a);
  atomicMax(&mOdd, o);
  __syncthreads();
  if (threadIdx.x == 0) {
    int m;
    if (mAll > 1u) m = 0;        // packed 1-byte bool
    else if (mOdd == 0u) m = 2;  // int64 (odd u32 words all zero)
    else m = 1;                  // int32
    *mode = m;
  }
}

__device__ __forceinline__ bool read_allow(const void* loc, int mode, int i) {
  if (mode == 0) return ((const uint8_t*)loc)[i] != 0;
  if (mode == 1) return ((const int*)loc)[i] != 0;
  return ((const uint32_t*)loc)[(size_t)i * 2] != 0;  // little-endian low word
}

// ---------------- prep: x transpose, weight transforms, BN fold ----------------
struct PrepArgs {
  const float* x; float* x0;
  const float* w[9]; float* wt[9];
  int O[9], C[9];
  const float* bn[11]; float* bns[11]; float* bnb[11];
  int bc[11];
};

__global__ void prep_k(PrepArgs pa) {
  int idx = blockIdx.x * 256 + threadIdx.x;
  if (idx < NROWS * 3) {               // x (B,3,N) -> x0 (B*N, 3)
    int c = idx % 3, r = idx / 3;
    int b = r >> 11, n = r & (NPTS - 1);
    pa.x0[idx] = pa.x[((size_t)b * 3 + c) * NPTS + n];
    return;
  }
  idx -= NROWS * 3;
  #pragma unroll
  for (int l = 0; l < 9; ++l) {
    int O = pa.O[l], C = pa.C[l];
    int n2 = (l == 8) ? O : 2 * O;
    int sz = C * n2;
    if (idx < sz) {
      int o = idx % n2, c = idx / n2;
      float v;
      if (l == 8) v = pa.w[l][(size_t)o * C + c];                     // plain transpose of w9
      else if (o < O) v = pa.w[l][(size_t)o * 2 * C + c];             // wA
      else v = pa.w[l][(size_t)(o - O) * 2 * C + C + c]
             - pa.w[l][(size_t)(o - O) * 2 * C + c];                  // wB - wA
      pa.wt[l][(size_t)c * n2 + o] = v;
      return;
    }
    idx -= sz;
  }
  #pragma unroll
  for (int i = 0; i < 11; ++i) {
    int C = pa.bc[i];
    if (idx < C) {
      float g = pa.bn[i][idx], b = pa.bn[i][C + idx];
      float m = pa.bn[i][2 * C + idx], v = pa.bn[i][3 * C + idx];
      float s = g * rsqrtf(v + 1e-5f);
      pa.bns[i][idx] = s;
      pa.bnb[i][idx] = b - m * s;
      return;
    }
    idx -= C;
  }
}

// ---------------- kNN: exact jax top_k replication (value desc, index asc) -----
__global__ __launch_bounds__(256) void knn_k(const float* __restrict__ geod,
                                             const void* __restrict__ loc,
                                             const int* __restrict__ modep,
                                             int* __restrict__ idxL,
                                             int* __restrict__ idxG) {
  int row = blockIdx.x;
  int b = row >> 11;
  int tid = threadIdx.x;
  int wid = tid >> 6, lane = tid & 63;
  int mode = *modep;
  const float* g = geod + (size_t)row * NPTS;

  float v[8]; bool al[8];
  float lmin = INFINITY;
  #pragma unroll
  for (int e = 0; e < 8; ++e) {
    int j = tid + 256 * e;
    v[e] = g[j];
    al[e] = read_allow(loc, mode, b * NPTS + j);
    lmin = fminf(lmin, v[e]);
  }
  __shared__ float sred[4];
  #pragma unroll
  for (int off = 32; off; off >>= 1) lmin = fminf(lmin, __shfl_xor(lmin, off));
  if (lane == 0) sred[wid] = lmin;
  __syncthreads();
  lmin = fminf(fminf(sred[0], sred[1]), fminf(sred[2], sred[3]));

  uint32_t smin = sortable_f32(lmin);
  unsigned long long keyL[8], keyG[8];
  #pragma unroll
  for (int e = 0; e < 8; ++e) {
    int j = tid + 256 * e;
    uint32_t sv = sortable_f32(v[e]);
    uint32_t kl = al[e] ? sv : smin;   // local conv: allowed = local_idx
    uint32_t kg = al[e] ? smin : sv;   // global conv: allowed = ~local_idx
    keyL[e] = ((unsigned long long)kl << 11) | (unsigned)(NPTS - 1 - j);
    keyG[e] = ((unsigned long long)kg << 11) | (unsigned)(NPTS - 1 - j);
  }

  // ping-pong shared slots: ONE barrier per extraction.
  // write of slot (it&1) happens after barrier of it-1, which in turn
  // guarantees every thread finished reading slot ((it-2)&1) == (it&1).
  __shared__ unsigned long long skey[2][4];
  auto runsel = [&](unsigned long long* key, int K, int* outp) {
    unsigned long long tmax = key[0];
    #pragma unroll
    for (int e = 1; e < 8; ++e) tmax = tmax > key[e] ? tmax : key[e];
    for (int it = 0; it < K; ++it) {
      unsigned long long m = tmax;
      #pragma unroll
      for (int off = 32; off; off >>= 1) {
        unsigned lo = __shfl_xor((unsigned)m, off);
        unsigned hi = __shfl_xor((unsigned)(m >> 32), off);
        unsigned long long om = ((unsigned long long)hi << 32) | lo;
        m = m > om ? m : om;
      }
      int s = it & 1;
      if (lane == 0) skey[s][wid] = m;
      __syncthreads();
      unsigned long long M = skey[s][0];
      #pragma unroll
      for (int w = 1; w < 4; ++w) M = M > skey[s][w] ? M : skey[s][w];
      int j = (NPTS - 1) - (int)(M & (unsigned long long)(NPTS - 1));
      if (tid == 0) outp[it] = j;
      if ((j & 255) == tid) {          // this thread owned the extracted key
        key[j >> 8] = 0ull;
        tmax = key[0];
        #pragma unroll
        for (int e = 1; e < 8; ++e) tmax = tmax > key[e] ? tmax : key[e];
      }
      // no trailing barrier: next write targets the other slot
    }
  };
  runsel(keyL, 16, idxL + (size_t)row * 16);
  runsel(keyG, 32, idxG + (size_t)row * 32);
}

// ---------------- fp32 tiled GEMM 64x64: C = A(MxK) * Bt(KxN2) ----------------
#define BM 64
#define BNC 64
#define BKC 16

__global__ __launch_bounds__(256) void gemm_k(const float* __restrict__ A, int lda,
                                              const float* __restrict__ Bt, int K, int N2,
                                              float* __restrict__ C, int ldc,
                                              const float* __restrict__ sc,
                                              const float* __restrict__ bi, int act) {
  __shared__ float As[BKC][BM + 4];   // row stride 272B = 16B-aligned
  __shared__ float Bs[BKC][BNC + 4];
  int tid = threadIdx.x;
  int tx = tid & 15, ty = tid >> 4;
  int m0 = blockIdx.x * BM, n0 = blockIdx.y * BNC;
  float acc[4][4] = {};
  for (int k0 = 0; k0 < K; k0 += BKC) {
    #pragma unroll
    for (int i = tid; i < BM * BKC; i += 256) {
      int kk = i & 15, mm = i >> 4;
      int kg = k0 + kk;
      As[kk][mm] = (kg < K) ? A[(size_t)(m0 + mm) * lda + kg] : 0.f;
    }
    #pragma unroll
    for (int i = tid; i < BKC * BNC; i += 256) {
      int nn = i & 63, kk = i >> 6;
      int kg = k0 + kk;
      Bs[kk][nn] = (kg < K) ? Bt[(size_t)kg * N2 + n0 + nn] : 0.f;
    }
    __syncthreads();
    #pragma unroll
    for (int k = 0; k < BKC; ++k) {
      float4 a4 = *(const float4*)&As[k][tx * 4];
      float4 b4 = *(const float4*)&Bs[k][ty * 4];
      float a[4] = {a4.x, a4.y, a4.z, a4.w};
      float bb[4] = {b4.x, b4.y, b4.z, b4.w};
      #pragma unroll
      for (int i2 = 0; i2 < 4; ++i2)
        #pragma unroll
        for (int j2 = 0; j2 < 4; ++j2)
          acc[i2][j2] = fmaf(a[i2], bb[j2], acc[i2][j2]);
    }
    __syncthreads();
  }
  #pragma unroll
  for (int i2 = 0; i2 < 4; ++i2) {
    int m = m0 + tx * 4 + i2;
    float4 o4;
    float* ov = (float*)&o4;
    #pragma unroll
    for (int j2 = 0; j2 < 4; ++j2) {
      int n = n0 + ty * 4 + j2;
      float vv = acc[i2][j2];
      if (act) {
        vv = fmaf(vv, sc[n], bi[n]);
        vv = vv >= 0.f ? vv : LNEG * vv;
      }
      ov[j2] = vv;
    }
    *(float4*)&C[(size_t)m * ldc + n0 + ty * 4] = o4;
  }
}

// ---------------- fp32 tiled GEMM 128x128 (8x8/thread) for the big layers ------
#define BM2 128
#define BN2 128
#define BK2 16

__global__ __launch_bounds__(256) void gemm128_k(const float* __restrict__ A, int lda,
                                                 const float* __restrict__ Bt, int K, int N2,
                                                 float* __restrict__ C, int ldc,
                                                 const float* __restrict__ sc,
                                                 const float* __restrict__ bi, int act) {
  __shared__ float As[BK2][BM2 + 4];  // row stride 528B = 16B-aligned
  __shared__ float Bs[BK2][BN2 + 4];
  int tid = threadIdx.x;
  int tx = tid & 15, ty = tid >> 4;
  int m0 = blockIdx.x * BM2, n0 = blockIdx.y * BN2;
  float acc[8][8] = {};
  for (int k0 = 0; k0 < K; k0 += BK2) {
    #pragma unroll
    for (int i = tid; i < BM2 * BK2; i += 256) {
      int kk = i & 15, mm = i >> 4;
      int kg = k0 + kk;
      As[kk][mm] = (kg < K) ? A[(size_t)(m0 + mm) * lda + kg] : 0.f;
    }
    #pragma unroll
    for (int i = tid; i < BK2 * BN2; i += 256) {
      int nn = i & 127, kk = i >> 7;
      int kg = k0 + kk;
      Bs[kk][nn] = (kg < K) ? Bt[(size_t)kg * N2 + n0 + nn] : 0.f;
    }
    __syncthreads();
    #pragma unroll
    for (int k = 0; k < BK2; ++k) {
      float a[8], bb[8];
      *(float4*)&a[0]  = *(const float4*)&As[k][tx * 8];
      *(float4*)&a[4]  = *(const float4*)&As[k][tx * 8 + 4];
      *(float4*)&bb[0] = *(const float4*)&Bs[k][ty * 8];
      *(float4*)&bb[4] = *(const float4*)&Bs[k][ty * 8 + 4];
      #pragma unroll
      for (int i2 = 0; i2 < 8; ++i2)
        #pragma unroll
        for (int j2 = 0; j2 < 8; ++j2)
          acc[i2][j2] = fmaf(a[i2], bb[j2], acc[i2][j2]);
    }
    __syncthreads();
  }
  #pragma unroll
  for (int i2 = 0; i2 < 8; ++i2) {
    int m = m0 + tx * 8 + i2;
    float4 o4a, o4b;
    float* ov = (float*)&o4a;
    float* ow = (float*)&o4b;
    #pragma unroll
    for (int j2 = 0; j2 < 8; ++j2) {
      int n = n0 + ty * 8 + j2;
      float vv = acc[i2][j2];
      if (act) {
        vv = fmaf(vv, sc[n], bi[n]);
        vv = vv >= 0.f ? vv : LNEG * vv;
      }
      if (j2 < 4) ov[j2] = vv; else ow[j2 - 4] = vv;
    }
    *(float4*)&C[(size_t)m * ldc + n0 + ty * 8] = o4a;
    *(float4*)&C[(size_t)m * ldc + n0 + ty * 8 + 4] = o4b;
  }
}

// ---------------- gather-max + BN + leaky: one wave per point ------------------
template<int K, int O>
__global__ __launch_bounds__(256) void gather_k(const float* __restrict__ z,
                                                const int* __restrict__ idx,
                                                const float* __restrict__ scale,
                                                const float* __restrict__ bias,
                                                float* __restrict__ outp) {
  constexpr int LDZ = 2 * O;
  int wid = threadIdx.x >> 6, lane = threadIdx.x & 63;
  int point = (blockIdx.x << 2) + wid;
  int b = point >> 11;
  const int* ip = idx + (size_t)point * K;
  int jj[K];
  #pragma unroll
  for (int k = 0; k < K; ++k) jj[k] = ip[k];
  #pragma unroll
  for (int c0 = 0; c0 < O; c0 += 64) {
    int c = c0 + lane;
    float mx = -INFINITY, mn = INFINITY;
    #pragma unroll
    for (int k = 0; k < K; ++k) {
      float v = z[(size_t)((b << 11) + jj[k]) * LDZ + c];
      mx = fmaxf(mx, v);
      mn = fminf(mn, v);
    }
    float zc = z[(size_t)point * LDZ + O + c];
    float s = scale[c], bb = bias[c];
    float val = (s >= 0.f ? mx : mn) + zc;     // max commutes through monotone BN+leaky
    float t = fmaf(val, s, bb);
    outp[(size_t)point * 512 + c] = t >= 0.f ? t : LNEG * t;
  }
}

// ---------------- xm = local_idx ? xcatL : xcatG ------------------------------
__global__ __launch_bounds__(256) void select_k(const float* __restrict__ xl,
                                                const float* __restrict__ xg,
                                                const void* __restrict__ loc,
                                                const int* __restrict__ modep,
                                                float* __restrict__ xm) {
  int i = blockIdx.x * 256 + threadIdx.x;   // over NROWS*128 float4
  int row = i >> 7;
  int mode = *modep;
  bool l = read_allow(loc, mode, row);
  const float4* s = (const float4*)(l ? xl : xg);
  ((float4*)xm)[i] = s[i];
}

// ---------------- per-(b,channel) max & mean over n ---------------------------
__global__ __launch_bounds__(256) void reduce_np_k(const float* __restrict__ y,
                                                   float* __restrict__ p) {
  int b = blockIdx.x >> 4, cb = blockIdx.x & 15;
  int wid = threadIdx.x >> 6, lane = threadIdx.x & 63;
  int c = cb * 64 + lane;
  float mx = -INFINITY, sm = 0.f;
  for (int n = wid; n < NPTS; n += 4) {
    float v = y[((size_t)(b * NPTS + n)) * 1024 + c];
    mx = fmaxf(mx, v);
    sm += v;
  }
  __shared__ float smx[4][64], ssm[4][64];
  smx[wid][lane] = mx;
  ssm[wid][lane] = sm;
  __syncthreads();
  if (wid == 0) {
    #pragma unroll
    for (int w = 1; w < 4; ++w) { mx = fmaxf(mx, smx[w][lane]); sm += ssm[w][lane]; }
    p[b * 2048 + c] = mx;
    p[b * 2048 + 1024 + c] = sm * (1.f / 2048.f);
  }
}

// ---------------- MLP layer kernels: one wave per output neuron ---------------
// layer 1: in p[4][2048], w lin1_w[512][2048]; BN10+leaky -> h1[4][512]
__global__ __launch_bounds__(256) void mlp1_k(const float* __restrict__ p,
                                              const float* __restrict__ w,
                                              const float* __restrict__ s10,
                                              const float* __restrict__ b10,
                                              float* __restrict__ h1) {
  int o = (blockIdx.x << 2) + (threadIdx.x >> 6);
  int lane = threadIdx.x & 63;
  const float4* wr = (const float4*)(w + (size_t)o * 2048);
  float acc[NB] = {};
  for (int i = lane; i < 512; i += 64) {
    float4 wv = wr[i];
    #pragma unroll
    for (int b = 0; b < NB; ++b) {
      float4 pv = ((const float4*)(p + b * 2048))[i];
      acc[b] += wv.x * pv.x + wv.y * pv.y + wv.z * pv.z + wv.w * pv.w;
    }
  }
  #pragma unroll
  for (int off = 32; off; off >>= 1)
    #pragma unroll
    for (int b = 0; b < NB; ++b) acc[b] += __shfl_xor(acc[b], off);
  if (lane == 0) {
    float sc = s10[o], bc = b10[o];
    #pragma unroll
    for (int b = 0; b < NB; ++b) {
      float t = fmaf(acc[b], sc, bc);
      h1[b * 512 + o] = t >= 0.f ? t : LNEG * t;
    }
  }
}

// layer 2: in h1[4][512], w lin2_w[256][512] + lin2_b; BN11+leaky -> h2[4][256]
__global__ __launch_bounds__(256) void mlp2_k(const float* __restrict__ h1,
                                              const float* __restrict__ w,
                                              const float* __restrict__ l2b,
                                              const float* __restrict__ s11,
                                              const float* __restrict__ b11,
                                              float* __restrict__ h2) {
  int o = (blockIdx.x << 2) + (threadIdx.x >> 6);
  int lane = threadIdx.x & 63;
  const float4* wr = (const float4*)(w + (size_t)o * 512);
  float acc[NB] = {};
  for (int i = lane; i < 128; i += 64) {
    float4 wv = wr[i];
    #pragma unroll
    for (int b = 0; b < NB; ++b) {
      float4 pv = ((const float4*)(h1 + b * 512))[i];
      acc[b] += wv.x * pv.x + wv.y * pv.y + wv.z * pv.z + wv.w * pv.w;
    }
  }
  #pragma unroll
  for (int off = 32; off; off >>= 1)
    #pragma unroll
    for (int b = 0; b < NB; ++b) acc[b] += __shfl_xor(acc[b], off);
  if (lane == 0) {
    float bl = l2b[o], sc = s11[o], bc = b11[o];
    #pragma unroll
    for (int b = 0; b < NB; ++b) {
      float t = fmaf(acc[b] + bl, sc, bc);
      h2[b * 256 + o] = t >= 0.f ? t : LNEG * t;
    }
  }
}

// layer 3: in h2[4][256], w lin3_w[40][256] + lin3_b -> out[4][40]
__global__ __launch_bounds__(256) void mlp3_k(const float* __restrict__ h2,
                                              const float* __restrict__ w,
                                              const float* __restrict__ l3b,
                                              float* __restrict__ outp) {
  int o = (blockIdx.x << 2) + (threadIdx.x >> 6);
  int lane = threadIdx.x & 63;
  if (o >= 40) return;
  const float4* wr = (const float4*)(w + (size_t)o * 256);
  float acc[NB] = {};
  for (int i = lane; i < 64; i += 64) {
    float4 wv = wr[i];
    #pragma unroll
    for (int b = 0; b < NB; ++b) {
      float4 pv = ((const float4*)(h2 + b * 256))[i];
      acc[b] += wv.x * pv.x + wv.y * pv.y + wv.z * pv.z + wv.w * pv.w;
    }
  }
  #pragma unroll
  for (int off = 32; off; off >>= 1)
    #pragma unroll
    for (int b = 0; b < NB; ++b) acc[b] += __shfl_xor(acc[b], off);
  if (lane == 0) {
    float bl = l3b[o];
    #pragma unroll
    for (int b = 0; b < NB; ++b) outp[b * 40 + o] = acc[b] + bl;
  }
}

// ---------------- host orchestration ------------------------------------------
extern "C" void kernel_launch(void* const* d_in, const int* in_sizes, int n_in,
                              void* d_out, int out_size, void* d_ws, size_t ws_size,
                              hipStream_t stream) {
  const float* x = (const float*)d_in[0];
  const void* loc = d_in[1];
  const float* geod = (const float*)d_in[2];
  const float* w[9];
  for (int i = 0; i < 9; ++i) w[i] = (const float*)d_in[3 + i];
  const float* bn[11];
  for (int i = 0; i < 11; ++i) bn[i] = (const float*)d_in[12 + i];
  const float* l1w = (const float*)d_in[23];
  const float* l2w = (const float*)d_in[24];
  const float* l2b = (const float*)d_in[25];
  const float* l3w = (const float*)d_in[26];
  const float* l3b = (const float*)d_in[27];
  float* outp = (float*)d_out;

  char* base = (char*)d_ws;
  size_t off = 0;
  auto alloc = [&](size_t bytes) -> void* {
    void* p = base + off;
    off += (bytes + 255) & ~(size_t)255;
    return p;
  };
  int* mode = (int*)alloc(4);
  float* x0 = (float*)alloc((size_t)NROWS * 3 * 4);
  int* idxL = (int*)alloc((size_t)NROWS * 16 * 4);
  int* idxG = (int*)alloc((size_t)NROWS * 32 * 4);
  static const int Oc[9] = {64, 64, 128, 256, 64, 64, 128, 256, 1024};
  static const int Cc[9] = {3, 64, 64, 128, 3, 64, 64, 128, 512};
  float* wt[9];
  for (int l = 0; l < 9; ++l) {
    int n2 = (l == 8) ? Oc[l] : 2 * Oc[l];
    wt[l] = (float*)alloc((size_t)Cc[l] * n2 * 4);
  }
  static const int bc[11] = {64, 64, 128, 256, 64, 64, 128, 256, 1024, 512, 256};
  float *bns[11], *bnb[11];
  for (int i = 0; i < 11; ++i) {
    bns[i] = (float*)alloc((size_t)bc[i] * 4);
    bnb[i] = (float*)alloc((size_t)bc[i] * 4);
  }
  float* z = (float*)alloc((size_t)NROWS * 1024 * 4);      // reused: conv z / layer-9 y
  float* xcatL = (float*)alloc((size_t)NROWS * 512 * 4);
  float* xcatG = (float*)alloc((size_t)NROWS * 512 * 4);
  float* xm = (float*)alloc((size_t)NROWS * 512 * 4);
  float* pbuf = (float*)alloc((size_t)NB * 2048 * 4);
  float* h1 = (float*)alloc((size_t)NB * 512 * 4);
  float* h2 = (float*)alloc((size_t)NB * 256 * 4);

  detect_mode_k<<<1, 256, 0, stream>>>((const uint32_t*)loc, mode);

  PrepArgs pa;
  pa.x = x; pa.x0 = x0;
  for (int l = 0; l < 9; ++l) { pa.w[l] = w[l]; pa.wt[l] = wt[l]; pa.O[l] = Oc[l]; pa.C[l] = Cc[l]; }
  for (int i = 0; i < 11; ++i) { pa.bn[i] = bn[i]; pa.bns[i] = bns[i]; pa.bnb[i] = bnb[i]; pa.bc[i] = bc[i]; }
  int total = NROWS * 3;
  for (int l = 0; l < 9; ++l) total += Cc[l] * ((l == 8) ? Oc[l] : 2 * Oc[l]);
  for (int i = 0; i < 11; ++i) total += bc[i];
  prep_k<<<(total + 255) / 256, 256, 0, stream>>>(pa);

  knn_k<<<NROWS, 256, 0, stream>>>(geod, loc, mode, idxL, idxG);

  auto gemm = [&](const float* A, int lda, const float* Bt, int K, int N2, float* C, int ldc,
                  const float* sc, const float* bi, int act) {
    if (N2 >= 512) {
      dim3 grid(NROWS / BM2, N2 / BN2);
      gemm128_k<<<grid, 256, 0, stream>>>(A, lda, Bt, K, N2, C, ldc, sc, bi, act);
    } else {
      dim3 grid(NROWS / BM, N2 / BNC);
      gemm_k<<<grid, 256, 0, stream>>>(A, lda, Bt, K, N2, C, ldc, sc, bi, act);
    }
  };
  auto gather = [&](int K, int O, const int* idx, const float* sc, const float* bi, float* op) {
    dim3 grid(NROWS / 4);
    if (K == 16) {
      if (O == 64)       gather_k<16, 64><<<grid, 256, 0, stream>>>(z, idx, sc, bi, op);
      else if (O == 128) gather_k<16, 128><<<grid, 256, 0, stream>>>(z, idx, sc, bi, op);
      else               gather_k<16, 256><<<grid, 256, 0, stream>>>(z, idx, sc, bi, op);
    } else {
      if (O == 64)       gather_k<32, 64><<<grid, 256, 0, stream>>>(z, idx, sc, bi, op);
      else if (O == 128) gather_k<32, 128><<<grid, 256, 0, stream>>>(z, idx, sc, bi, op);
      else               gather_k<32, 256><<<grid, 256, 0, stream>>>(z, idx, sc, bi, op);
    }
  };

  static const int coff[4] = {0, 64, 128, 256};
  for (int l = 0; l < 4; ++l) {   // local chain (K=16, w1-4, bn1-4)
    const float* A = (l == 0) ? x0 : (xcatL + coff[l - 1]);
    int lda = (l == 0) ? 3 : 512;
    gemm(A, lda, wt[l], Cc[l], 2 * Oc[l], z, 2 * Oc[l], nullptr, nullptr, 0);
    gather(16, Oc[l], idxL, bns[l], bnb[l], xcatL + coff[l]);
  }
  for (int l = 0; l < 4; ++l) {   // global chain (K=32, w5-8, bn5-8)
    const float* A = (l == 0) ? x0 : (xcatG + coff[l - 1]);
    int lda = (l == 0) ? 3 : 512;
    gemm(A, lda, wt[4 + l], Cc[4 + l], 2 * Oc[4 + l], z, 2 * Oc[4 + l], nullptr, nullptr, 0);
    gather(32, Oc[4 + l], idxG, bns[4 + l], bnb[4 + l], xcatG + coff[l]);
  }

  select_k<<<(NROWS * 512 / 4) / 256, 256, 0, stream>>>(xcatL, xcatG, loc, mode, xm);
  gemm(xm, 512, wt[8], 512, 1024, z, 1024, bns[8], bnb[8], 1);   // layer 9 + BN9 + leaky fused
  reduce_np_k<<<NB * 16, 256, 0, stream>>>(z, pbuf);
  mlp1_k<<<128, 256, 0, stream>>>(pbuf, l1w, bns[9], bnb[9], h1);
  mlp2_k<<<64, 256, 0, stream>>>(h1, l2w, l2b, bns[10], bnb[10], h2);
  mlp3_k<<<10, 256, 0, stream>>>(h2, l3w, l3b, outp);
}